// Round 4
// baseline (38.229 us; speedup 1.0000x reference)
//
#include <hip/hip_runtime.h>
#include <hip/hip_bf16.h>
#include <math.h>

#define D_MODEL 512
#define N_PEAKS 500
#define BATCH   1024
#define BLOCK   256
#define SPLIT   2
#define NPB     (N_PEAKS / SPLIT)   // 250 peaks per block

// out[b][2k]   = sum_n w[b,n] * sin(idx[b,n] * omega_k)
// out[b][2k+1] = sum_n w[b,n] * cos(idx[b,n] * omega_k)
// idx = ceil(loc*10), omega_k = exp(2k * -ln(10000)/512); pe row 0 is zeroed
// in the reference -> mask idx==0 peaks.
//
// R4 structure: the n-sum is split across 2 blocks per batch row so the chip
// reaches full wave residency (4096 -> 8192 waves; 16 -> 32 waves/CU). The
// two partials are combined with exactly TWO f32 atomic adds per output
// element: a 2-operand f32 add is commutative, so the result is bitwise
// deterministic regardless of block arrival order. d_out is zeroed in-stream
// (graph-capturable memset) before the kernel.
__global__ __launch_bounds__(BLOCK)
void SpectrumEncoding_84164179132426_kernel(const float* __restrict__ loc,
                                            const float* __restrict__ inten,
                                            float* __restrict__ out) {
    __shared__ float2 s_iw[NPB];   // {ceil(loc*10) as float, masked weight}

    const int b    = blockIdx.x >> 1;
    const int half = blockIdx.x & 1;
    const int t    = threadIdx.x;

    const int base = b * N_PEAKS + half * NPB;
    if (t < NPB) {                       // 250 < 256: single staging pass
        float l    = loc[base + t];
        float idxf = ceilf(l * 10.0f);   // matches jnp.ceil(loc*10)
        float w    = inten[base + t];
        s_iw[t] = make_float2(idxf, (idxf == 0.0f) ? 0.0f : w);
    }
    __syncthreads();

    // omega_k / (2*pi) in f64 once per thread (table-grade precision).
    const double cd = -log(10000.0) / (double)D_MODEL;
    const float wk_rev = (float)(exp((double)(2 * t) * cd) / (2.0 * M_PI));

    float acc_s = 0.0f, acc_c = 0.0f;

#pragma unroll 5
    for (int n = 0; n < NPB; ++n) {
        const float2 iw  = s_iw[n];                      // broadcast ds_read_b64
        const float  rev = iw.x * wk_rev;                // angle in revolutions
        const float  r   = __builtin_amdgcn_fractf(rev); // v_fract_f32 -> [0,1)
        acc_s = fmaf(iw.y, __builtin_amdgcn_sinf(r), acc_s);  // v_sin_f32
        acc_c = fmaf(iw.y, __builtin_amdgcn_cosf(r), acc_c);  // v_cos_f32
    }

    float* o = out + b * D_MODEL + 2 * t;
#if defined(__gfx950__) || defined(__AMDGCN__)
    unsafeAtomicAdd(o,     acc_s);       // native global_atomic_add_f32
    unsafeAtomicAdd(o + 1, acc_c);
#else
    atomicAdd(o,     acc_s);
    atomicAdd(o + 1, acc_c);
#endif
}

extern "C" void kernel_launch(void* const* d_in, const int* in_sizes, int n_in,
                              void* d_out, int out_size, void* d_ws, size_t ws_size,
                              hipStream_t stream) {
    const float* loc   = (const float*)d_in[0];   // [1024, 500] f32
    const float* inten = (const float*)d_in[1];   // [1024, 500] f32
    // d_in[2] (pe table) intentionally unused: recomputed analytically.
    float*       out   = (float*)d_out;           // [1024, 512] f32

    hipMemsetAsync(d_out, 0, (size_t)BATCH * D_MODEL * sizeof(float), stream);
    SpectrumEncoding_84164179132426_kernel<<<BATCH * SPLIT, BLOCK, 0, stream>>>(loc, inten, out);
}